// Round 9
// baseline (661.584 us; speedup 1.0000x reference)
//
#include <hip/hip_runtime.h>
#include <hip/hip_bf16.h>

#define N_NODES 8192
#define D_DIM   256

typedef __attribute__((ext_vector_type(8))) short short8v;   // 8 x bf16 (4 VGPR)
typedef __attribute__((ext_vector_type(4))) float f32x4;

__device__ __forceinline__ float artanh_clip(float x) {
    x = fminf(x, 1.0f - 1e-7f);
    return 0.5f * logf((1.0f + x) / (1.0f - x));
}

__device__ __forceinline__ unsigned int pk2_bf16(float a, float b) {
    unsigned int lo = (unsigned int)__bfloat16_as_ushort(__float2bfloat16(a));
    unsigned int hi = (unsigned int)__bfloat16_as_ushort(__float2bfloat16(b));
    return lo | (hi << 16);
}

__device__ __forceinline__ void nt_store4(float4 v, float* p) {
    f32x4 w = {v.x, v.y, v.z, v.w};
    __builtin_nontemporal_store(w, (f32x4*)p);
}

// ---------------- K0: hyp_bias = proj(expmap0(bias)), plus b2 = ||hb||^2 ----
__global__ void k0_bias(const float* __restrict__ bias, float* __restrict__ hbg) {
    __shared__ float sp[4];
    __shared__ float s_g;
    int t = threadIdx.x;
    float u = bias[t];
    float v = u * u;
    #pragma unroll
    for (int o = 1; o < 64; o <<= 1) v += __shfl_xor(v, o);
    if ((t & 63) == 0) sp[t >> 6] = v;
    __syncthreads();
    if (t == 0) {
        float s  = sp[0] + sp[1] + sp[2] + sp[3];
        float un = fmaxf(sqrtf(s), 1e-15f);
        float t1 = tanhf(un);
        s_g = (t1 > 0.996f) ? (0.996f / un) : (t1 / un);
    }
    __syncthreads();
    float hb = s_g * u;
    hbg[t] = hb;
    float v2 = hb * hb;
    #pragma unroll
    for (int o = 1; o < 64; o <<= 1) v2 += __shfl_xor(v2, o);
    if ((t & 63) == 0) sp[t >> 6] = v2;
    __syncthreads();
    if (t == 0) hbg[256] = sp[0] + sp[1] + sp[2] + sp[3];
}

// ---------------- K1: HypLinear + logmap0 -> xtT (bf16, transposed [D][N]) --
__global__ __launch_bounds__(256) void k1_hyplinear(
    const float* __restrict__ x, const float* __restrict__ W,
    const float* __restrict__ hbg, __hip_bfloat16* __restrict__ xtT)
{
    __shared__ __align__(16) float sx[16][264];   // x tile; later reused for mx
    __shared__ __align__(16) float sw[256][36];   // W k-chunk [d][32]
    __shared__ float s_xn[16], s_P[16], s_Q[16];
    __shared__ float s_hb[256];
    __shared__ float s_b2;

    const int t  = threadIdx.x;
    const int r0 = blockIdx.x * 16;
    const int row = t >> 4;
    const int j16 = (t & 15) * 4;

    {   // stage x tile, coalesced
        #pragma unroll
        for (int i = 0; i < 4; i++)
            *(float4*)(&sx[row][j16 + 64 * i]) =
                *(const float4*)(x + (r0 + row) * 256 + j16 + 64 * i);
    }
    s_hb[t] = hbg[t];
    if (t == 0) s_b2 = hbg[256];
    __syncthreads();

    {   // per-row ||x||^2
        int r = t >> 4, j = t & 15;
        float s2 = 0.f;
        #pragma unroll
        for (int i = 0; i < 16; i++) { float v = sx[r][j + 16 * i]; s2 += v * v; }
        s2 += __shfl_xor(s2, 1); s2 += __shfl_xor(s2, 2);
        s2 += __shfl_xor(s2, 4); s2 += __shfl_xor(s2, 8);
        if (j == 0) s_xn[r] = s2;
    }

    float acc[16];
    #pragma unroll
    for (int r = 0; r < 16; r++) acc[r] = 0.f;

    for (int kc = 0; kc < 8; kc++) {
        __syncthreads();
        {   // stage W chunk [256][32]
            int c4 = (t & 7) * 4;
            #pragma unroll
            for (int i = 0; i < 8; i++) {
                int d = i * 32 + (t >> 3);
                *(float4*)(&sw[d][c4]) = *(const float4*)(W + d * 256 + kc * 32 + c4);
            }
        }
        __syncthreads();
        #pragma unroll
        for (int kk = 0; kk < 8; kk++) {
            float4 w4 = *(const float4*)(&sw[t][kk * 4]);
            #pragma unroll
            for (int r = 0; r < 16; r++) {
                float4 x4 = *(const float4*)(&sx[r][kc * 32 + kk * 4]);
                acc[r] = fmaf(x4.x, w4.x, acc[r]);
                acc[r] = fmaf(x4.y, w4.y, acc[r]);
                acc[r] = fmaf(x4.z, w4.z, acc[r]);
                acc[r] = fmaf(x4.w, w4.w, acc[r]);
            }
        }
    }
    __syncthreads();
    #pragma unroll
    for (int r = 0; r < 16; r++) sx[r][t] = acc[r];
    __syncthreads();

    {   // per-row sumsq(mx), dot(mx, hb) -> P, Q
        int r = t >> 4, j = t & 15;
        float s2 = 0.f, dt = 0.f;
        #pragma unroll
        for (int i = 0; i < 16; i++) {
            float v = sx[r][j + 16 * i];
            s2 += v * v;
            dt += v * s_hb[j + 16 * i];
        }
        s2 += __shfl_xor(s2, 1); s2 += __shfl_xor(s2, 2);
        s2 += __shfl_xor(s2, 4); s2 += __shfl_xor(s2, 8);
        dt += __shfl_xor(dt, 1); dt += __shfl_xor(dt, 2);
        dt += __shfl_xor(dt, 4); dt += __shfl_xor(dt, 8);
        if (j == 0) {
            float b2  = s_b2;
            float xn  = fmaxf(sqrtf(s_xn[r]), 1e-15f);
            float mx2 = s2;
            float mxn = fmaxf(sqrtf(mx2), 1e-15f);
            float at = artanh_clip(xn);
            float tt = tanhf(mxn / xn * at);
            float fr = tt / mxn;
            if (tt > 0.996f) fr = 0.996f / mxn;
            float mvn = fminf(tt, 0.996f);
            float x2  = mvn * mvn;
            float xy  = fr * dt;
            float cA  = 1.0f + 2.0f * xy + b2;
            float cB  = 1.0f - x2;
            float den = fmaxf(1.0f + 2.0f * xy + x2 * b2, 1e-15f);
            float P0 = cA * fr / den;
            float Q0 = cB / den;
            float hn = sqrtf(fmaxf(P0 * P0 * mx2 + 2.0f * P0 * Q0 * dt + Q0 * Q0 * b2, 0.0f));
            hn = fmaxf(hn, 1e-15f);
            float pf  = (hn > 0.996f) ? (0.996f / hn) : 1.0f;
            float hnp = fminf(hn, 0.996f);
            float lam = artanh_clip(hnp) / hnp;
            s_P[r] = lam * pf * P0;
            s_Q[r] = lam * pf * Q0;
        }
    }
    __syncthreads();

    {   // xt -> xtT (bf16, transposed)
        float hb = s_hb[t];
        unsigned int pk[8];
        #pragma unroll
        for (int r = 0; r < 16; r += 2) {
            float a0 = s_P[r]     * acc[r]     + s_Q[r]     * hb;
            float a1 = s_P[r + 1] * acc[r + 1] + s_Q[r + 1] * hb;
            pk[r >> 1] = pk2_bf16(a0, a1);
        }
        uint4* dst = (uint4*)(xtT + t * 8192 + r0);
        dst[0] = make_uint4(pk[0], pk[1], pk[2], pk[3]);
        dst[1] = make_uint4(pk[4], pk[5], pk[6], pk[7]);
    }
}

// ---------------- K2: fused m97-style GEMM + adj passthrough ----------------
// grid 512 = 64 m-tiles x 2 n-halves x 4 k-slabs; bx: m = bx&63 (same-m
// siblings share an XCD via bx%8), j = bx>>6, c = j&1, s = j>>1.
// BM=128, BN=128, BK=64, 256 thr / 4 waves (2x2), wave = 64x64 = 4x4 frags,
// 32 MFMA per wave per K-step. A: f32 regs (issue-early) -> nt passthrough
// (c==0 only) + cvt -> LDS bf16 [128][72] (pad: 2-way-free frag reads).
// B: direct 16B loads from L2-resident xtT. Partials -> ws (or atomicAdd).
__global__ __launch_bounds__(256) void k2_gemm(
    const float* __restrict__ adj,
    const __hip_bfloat16* __restrict__ xtT,
    float* __restrict__ out_h,
    float* __restrict__ out_adj,
    float* __restrict__ part)          // nullptr -> atomicAdd into out_h
{
    __shared__ __align__(16) char As[2][128 * 144];   // 36 KB total

    const int t    = threadIdx.x;
    const int lane = t & 63;
    const int wave = t >> 6;
    const int wm   = wave >> 1;          // 64-row half
    const int wn   = wave & 1;           // 64-col half
    const int bx   = blockIdx.x;
    const int m    = bx & 63;
    const int j    = bx >> 6;
    const int c    = j & 1;
    const int s    = j >> 1;
    const int m0   = m * 128;
    const int n0   = c * 128;
    const int kbase = s * 2048;          // 32 K-steps of 64

    // staging: thread t -> row t>>1, 128B half (t&1)
    const int srow  = t >> 1;
    const int shalf = t & 1;
    const float* aptr = adj     + (size_t)(m0 + srow) * 8192 + kbase + shalf * 32;
    float*       optr = out_adj + (size_t)(m0 + srow) * 8192 + kbase + shalf * 32;
    const int sbyte = srow * 144 + shalf * 64;

    // fragment indexing
    const int arow16 = lane & 15;
    const int g8     = lane >> 4;        // 0..3
    const int abyte0 = (wm * 64 + arow16) * 144 + 16 * g8;   // + mf*16*144 + ks*64
    const __hip_bfloat16* bbase =
        xtT + (size_t)(n0 + wn * 64 + arow16) * 8192 + kbase + 8 * g8;

    f32x4 acc[4][4];
    #pragma unroll
    for (int i = 0; i < 4; i++)
        #pragma unroll
        for (int k = 0; k < 4; k++) acc[i][k] = (f32x4){0.f, 0.f, 0.f, 0.f};

    float4 T[8];
    // prologue: stage tile 0
    #pragma unroll
    for (int i = 0; i < 8; i++) T[i] = *(const float4*)(aptr + i * 4);
    if (c == 0) {
        #pragma unroll
        for (int i = 0; i < 8; i++) nt_store4(T[i], optr + i * 4);
    }
    #pragma unroll
    for (int i = 0; i < 4; i++) {
        uint4 w;
        w.x = pk2_bf16(T[2*i].x, T[2*i].y);
        w.y = pk2_bf16(T[2*i].z, T[2*i].w);
        w.z = pk2_bf16(T[2*i+1].x, T[2*i+1].y);
        w.w = pk2_bf16(T[2*i+1].z, T[2*i+1].w);
        *(uint4*)(&As[0][sbyte + i * 16]) = w;
    }
    __syncthreads();

    int cur = 0;
    for (int kt = 0; kt < 32; kt++) {
        const bool hn = (kt + 1 < 32);
        // T14 issue-early: next A tile -> regs
        if (hn) {
            #pragma unroll
            for (int i = 0; i < 8; i++)
                T[i] = *(const float4*)(aptr + (kt + 1) * 64 + i * 4);
        }

        // B frags (L2) + A frags (LDS)
        short8v bf[4][2], af[4][2];
        #pragma unroll
        for (int nf = 0; nf < 4; nf++)
            #pragma unroll
            for (int ks = 0; ks < 2; ks++)
                bf[nf][ks] = *(const short8v*)(bbase + (size_t)nf * 16 * 8192 + kt * 64 + ks * 32);
        #pragma unroll
        for (int mf = 0; mf < 4; mf++)
            #pragma unroll
            for (int ks = 0; ks < 2; ks++)
                af[mf][ks] = *(const short8v*)(&As[cur][abyte0 + mf * 16 * 144 + ks * 64]);

        #pragma unroll
        for (int ks = 0; ks < 2; ks++)
            #pragma unroll
            for (int mf = 0; mf < 4; mf++)
                #pragma unroll
                for (int nf = 0; nf < 4; nf++)
                    acc[mf][nf] = __builtin_amdgcn_mfma_f32_16x16x32_bf16(
                        af[mf][ks], bf[nf][ks], acc[mf][nf], 0, 0, 0);

        if (hn) {   // write-late: passthrough + next LDS buffer
            if (c == 0) {
                #pragma unroll
                for (int i = 0; i < 8; i++)
                    nt_store4(T[i], optr + (kt + 1) * 64 + i * 4);
            }
            #pragma unroll
            for (int i = 0; i < 4; i++) {
                uint4 w;
                w.x = pk2_bf16(T[2*i].x, T[2*i].y);
                w.y = pk2_bf16(T[2*i].z, T[2*i].w);
                w.z = pk2_bf16(T[2*i+1].x, T[2*i+1].y);
                w.w = pk2_bf16(T[2*i+1].z, T[2*i+1].w);
                *(uint4*)(&As[cur ^ 1][sbyte + i * 16]) = w;
            }
        }
        __syncthreads();
        cur ^= 1;
    }

    // emit partials (C layout: col=lane&15, row=4*(lane>>4)+q)
    const int crow0 = 4 * (lane >> 4);
    const int ccol  = lane & 15;
    if (part) {
        float* pb = part + (size_t)s * N_NODES * D_DIM;
        #pragma unroll
        for (int mf = 0; mf < 4; mf++)
            #pragma unroll
            for (int nf = 0; nf < 4; nf++)
                #pragma unroll
                for (int q = 0; q < 4; q++)
                    pb[(size_t)(m0 + wm * 64 + mf * 16 + crow0 + q) * 256
                       + n0 + wn * 64 + nf * 16 + ccol] = acc[mf][nf][q];
    } else {
        #pragma unroll
        for (int mf = 0; mf < 4; mf++)
            #pragma unroll
            for (int nf = 0; nf < 4; nf++)
                #pragma unroll
                for (int q = 0; q < 4; q++)
                    atomicAdd(out_h + (size_t)(m0 + wm * 64 + mf * 16 + crow0 + q) * 256
                              + n0 + wn * 64 + nf * 16 + ccol, acc[mf][nf][q]);
    }
}

// ---------------- K3: partial-reduce (optional) + hyperbolic epilogue -------
__global__ __launch_bounds__(256) void k3_epilogue(
    float* __restrict__ h, const float* __restrict__ part)
{
    const int t = threadIdx.x;
    const int r = blockIdx.x * 16 + (t >> 4);
    const int j = t & 15;
    float* p = h + (size_t)r * 256 + j * 16;

    float4 v[4];
    if (part) {
        const size_t base = (size_t)r * 256 + j * 16;
        #pragma unroll
        for (int i = 0; i < 4; i++) {
            float4 a0 = *(const float4*)(part + base + 4 * i);
            float4 a1 = *(const float4*)(part + (size_t)N_NODES * D_DIM + base + 4 * i);
            float4 a2 = *(const float4*)(part + (size_t)2 * N_NODES * D_DIM + base + 4 * i);
            float4 a3 = *(const float4*)(part + (size_t)3 * N_NODES * D_DIM + base + 4 * i);
            v[i].x = a0.x + a1.x + a2.x + a3.x;
            v[i].y = a0.y + a1.y + a2.y + a3.y;
            v[i].z = a0.z + a1.z + a2.z + a3.z;
            v[i].w = a0.w + a1.w + a2.w + a3.w;
        }
    } else {
        #pragma unroll
        for (int i = 0; i < 4; i++) v[i] = *(const float4*)(p + 4 * i);
    }

    float s2 = 0.f, sp = 0.f;
    #pragma unroll
    for (int i = 0; i < 4; i++) {
        s2 += v[i].x * v[i].x + v[i].y * v[i].y + v[i].z * v[i].z + v[i].w * v[i].w;
        float px = fmaxf(v[i].x, 0.f), py = fmaxf(v[i].y, 0.f);
        float pz = fmaxf(v[i].z, 0.f), pw = fmaxf(v[i].w, 0.f);
        sp += px * px + py * py + pz * pz + pw * pw;
    }
    s2 += __shfl_xor(s2, 1); s2 += __shfl_xor(s2, 2); s2 += __shfl_xor(s2, 4); s2 += __shfl_xor(s2, 8);
    sp += __shfl_xor(sp, 1); sp += __shfl_xor(sp, 2); sp += __shfl_xor(sp, 4); sp += __shfl_xor(sp, 8);

    float ns = fmaxf(sqrtf(s2), 1e-15f);
    float t1 = tanhf(ns);
    float alpha = (t1 > 0.996f) ? (0.996f / ns) : (t1 / ns);   // expmap0+proj
    float nh = fminf(t1, 0.996f);
    float beta = artanh_clip(nh) / nh;                          // logmap0
    float ba = beta * alpha;
    float nxt = fmaxf(ba * sqrtf(sp), 1e-15f);                  // ||relu(xt)||
    float t2 = tanhf(nxt);
    float delta = (t2 > 0.996f) ? (0.996f / nxt) : (t2 / nxt);  // expmap0+proj
    float F = delta * ba;

    #pragma unroll
    for (int i = 0; i < 4; i++) {
        float4 o;
        o.x = F * fmaxf(v[i].x, 0.f);
        o.y = F * fmaxf(v[i].y, 0.f);
        o.z = F * fmaxf(v[i].z, 0.f);
        o.w = F * fmaxf(v[i].w, 0.f);
        *(float4*)(p + 4 * i) = o;
    }
}

extern "C" void kernel_launch(void* const* d_in, const int* in_sizes, int n_in,
                              void* d_out, int out_size, void* d_ws, size_t ws_size,
                              hipStream_t stream)
{
    const float* x    = (const float*)d_in[0];
    const float* adj  = (const float*)d_in[1];
    const float* W    = (const float*)d_in[2];
    const float* bias = (const float*)d_in[3];

    float* out_h   = (float*)d_out;
    float* out_adj = out_h + (size_t)N_NODES * D_DIM;

    const size_t xtT_bytes = (size_t)D_DIM * N_NODES * 2;       // 4 MB
    __hip_bfloat16* xtT = (__hip_bfloat16*)d_ws;
    float* hbg = (float*)((char*)d_ws + xtT_bytes);             // hb[256] + b2

    const size_t part_off   = xtT_bytes + 4096;
    const size_t part_bytes = (size_t)4 * N_NODES * D_DIM * sizeof(float);  // 32 MB
    const bool use_part = ws_size >= part_off + part_bytes;
    float* part = use_part ? (float*)((char*)d_ws + part_off) : nullptr;

    k0_bias<<<1, 256, 0, stream>>>(bias, hbg);
    k1_hyplinear<<<512, 256, 0, stream>>>(x, W, hbg, xtT);
    if (!use_part)
        hipMemsetAsync(out_h, 0, (size_t)N_NODES * D_DIM * sizeof(float), stream);
    k2_gemm<<<512, 256, 0, stream>>>(adj, xtT, out_h, out_adj, part);
    k3_epilogue<<<512, 256, 0, stream>>>(out_h, part);
}

// Round 10
// 307.308 us; speedup vs baseline: 2.1528x; 2.1528x over previous
//
#include <hip/hip_runtime.h>
#include <hip/hip_bf16.h>

#define N_NODES 8192
#define D_DIM   256

typedef __attribute__((ext_vector_type(8))) short short8v;   // 8 x bf16 (4 VGPR)
typedef __attribute__((ext_vector_type(4))) float f32x4;

__device__ __forceinline__ float artanh_clip(float x) {
    x = fminf(x, 1.0f - 1e-7f);
    return 0.5f * logf((1.0f + x) / (1.0f - x));
}

__device__ __forceinline__ ushort4 cvt4_bf16(float4 v) {
    ushort4 b;
    b.x = __bfloat16_as_ushort(__float2bfloat16(v.x));
    b.y = __bfloat16_as_ushort(__float2bfloat16(v.y));
    b.z = __bfloat16_as_ushort(__float2bfloat16(v.z));
    b.w = __bfloat16_as_ushort(__float2bfloat16(v.w));
    return b;
}

__device__ __forceinline__ unsigned int pk2_bf16(float a, float b) {
    unsigned int lo = (unsigned int)__bfloat16_as_ushort(__float2bfloat16(a));
    unsigned int hi = (unsigned int)__bfloat16_as_ushort(__float2bfloat16(b));
    return lo | (hi << 16);
}

__device__ __forceinline__ void nt_store4(float4 v, float* p) {
    f32x4 w = {v.x, v.y, v.z, v.w};
    __builtin_nontemporal_store(w, (f32x4*)p);
}

// ---------------- K0: hyp_bias = proj(expmap0(bias)), plus b2 = ||hb||^2 ----
__global__ void k0_bias(const float* __restrict__ bias, float* __restrict__ hbg) {
    __shared__ float sp[4];
    __shared__ float s_g;
    int t = threadIdx.x;
    float u = bias[t];
    float v = u * u;
    #pragma unroll
    for (int o = 1; o < 64; o <<= 1) v += __shfl_xor(v, o);
    if ((t & 63) == 0) sp[t >> 6] = v;
    __syncthreads();
    if (t == 0) {
        float s  = sp[0] + sp[1] + sp[2] + sp[3];
        float un = fmaxf(sqrtf(s), 1e-15f);
        float t1 = tanhf(un);
        s_g = (t1 > 0.996f) ? (0.996f / un) : (t1 / un);
    }
    __syncthreads();
    float hb = s_g * u;
    hbg[t] = hb;
    float v2 = hb * hb;
    #pragma unroll
    for (int o = 1; o < 64; o <<= 1) v2 += __shfl_xor(v2, o);
    if ((t & 63) == 0) sp[t >> 6] = v2;
    __syncthreads();
    if (t == 0) hbg[256] = sp[0] + sp[1] + sp[2] + sp[3];
}

// ---------------- K1: HypLinear + logmap0 -> xtT (bf16, transposed [D][N]) --
__global__ __launch_bounds__(256) void k1_hyplinear(
    const float* __restrict__ x, const float* __restrict__ W,
    const float* __restrict__ hbg, __hip_bfloat16* __restrict__ xtT)
{
    __shared__ __align__(16) float sx[16][264];   // x tile; later reused for mx
    __shared__ __align__(16) float sw[256][36];   // W k-chunk [d][32]
    __shared__ float s_xn[16], s_P[16], s_Q[16];
    __shared__ float s_hb[256];
    __shared__ float s_b2;

    const int t  = threadIdx.x;
    const int r0 = blockIdx.x * 16;
    const int row = t >> 4;
    const int j16 = (t & 15) * 4;

    {   // stage x tile, coalesced
        #pragma unroll
        for (int i = 0; i < 4; i++)
            *(float4*)(&sx[row][j16 + 64 * i]) =
                *(const float4*)(x + (r0 + row) * 256 + j16 + 64 * i);
    }
    s_hb[t] = hbg[t];
    if (t == 0) s_b2 = hbg[256];
    __syncthreads();

    {   // per-row ||x||^2
        int r = t >> 4, j = t & 15;
        float s2 = 0.f;
        #pragma unroll
        for (int i = 0; i < 16; i++) { float v = sx[r][j + 16 * i]; s2 += v * v; }
        s2 += __shfl_xor(s2, 1); s2 += __shfl_xor(s2, 2);
        s2 += __shfl_xor(s2, 4); s2 += __shfl_xor(s2, 8);
        if (j == 0) s_xn[r] = s2;
    }

    float acc[16];
    #pragma unroll
    for (int r = 0; r < 16; r++) acc[r] = 0.f;

    for (int kc = 0; kc < 8; kc++) {
        __syncthreads();
        {   // stage W chunk [256][32]
            int c4 = (t & 7) * 4;
            #pragma unroll
            for (int i = 0; i < 8; i++) {
                int d = i * 32 + (t >> 3);
                *(float4*)(&sw[d][c4]) = *(const float4*)(W + d * 256 + kc * 32 + c4);
            }
        }
        __syncthreads();
        #pragma unroll
        for (int kk = 0; kk < 8; kk++) {
            float4 w4 = *(const float4*)(&sw[t][kk * 4]);
            #pragma unroll
            for (int r = 0; r < 16; r++) {
                float4 x4 = *(const float4*)(&sx[r][kc * 32 + kk * 4]);
                acc[r] = fmaf(x4.x, w4.x, acc[r]);
                acc[r] = fmaf(x4.y, w4.y, acc[r]);
                acc[r] = fmaf(x4.z, w4.z, acc[r]);
                acc[r] = fmaf(x4.w, w4.w, acc[r]);
            }
        }
    }
    __syncthreads();
    #pragma unroll
    for (int r = 0; r < 16; r++) sx[r][t] = acc[r];
    __syncthreads();

    {   // per-row sumsq(mx), dot(mx, hb) -> P, Q
        int r = t >> 4, j = t & 15;
        float s2 = 0.f, dt = 0.f;
        #pragma unroll
        for (int i = 0; i < 16; i++) {
            float v = sx[r][j + 16 * i];
            s2 += v * v;
            dt += v * s_hb[j + 16 * i];
        }
        s2 += __shfl_xor(s2, 1); s2 += __shfl_xor(s2, 2);
        s2 += __shfl_xor(s2, 4); s2 += __shfl_xor(s2, 8);
        dt += __shfl_xor(dt, 1); dt += __shfl_xor(dt, 2);
        dt += __shfl_xor(dt, 4); dt += __shfl_xor(dt, 8);
        if (j == 0) {
            float b2  = s_b2;
            float xn  = fmaxf(sqrtf(s_xn[r]), 1e-15f);
            float mx2 = s2;
            float mxn = fmaxf(sqrtf(mx2), 1e-15f);
            float at = artanh_clip(xn);
            float tt = tanhf(mxn / xn * at);
            float fr = tt / mxn;
            if (tt > 0.996f) fr = 0.996f / mxn;
            float mvn = fminf(tt, 0.996f);
            float x2  = mvn * mvn;
            float xy  = fr * dt;
            float cA  = 1.0f + 2.0f * xy + b2;
            float cB  = 1.0f - x2;
            float den = fmaxf(1.0f + 2.0f * xy + x2 * b2, 1e-15f);
            float P0 = cA * fr / den;
            float Q0 = cB / den;
            float hn = sqrtf(fmaxf(P0 * P0 * mx2 + 2.0f * P0 * Q0 * dt + Q0 * Q0 * b2, 0.0f));
            hn = fmaxf(hn, 1e-15f);
            float pf  = (hn > 0.996f) ? (0.996f / hn) : 1.0f;
            float hnp = fminf(hn, 0.996f);
            float lam = artanh_clip(hnp) / hnp;
            s_P[r] = lam * pf * P0;
            s_Q[r] = lam * pf * Q0;
        }
    }
    __syncthreads();

    {   // xt -> xtT (bf16, transposed)
        float hb = s_hb[t];
        unsigned int pk[8];
        #pragma unroll
        for (int r = 0; r < 16; r += 2) {
            float a0 = s_P[r]     * acc[r]     + s_Q[r]     * hb;
            float a1 = s_P[r + 1] * acc[r + 1] + s_Q[r + 1] * hb;
            pk[r >> 1] = pk2_bf16(a0, a1);
        }
        uint4* dst = (uint4*)(xtT + t * 8192 + r0);
        dst[0] = make_uint4(pk[0], pk[1], pk[2], pk[3]);
        dst[1] = make_uint4(pk[4], pk[5], pk[6], pk[7]);
    }
}

// ---------------- K2: R3 structure, atomics removed, BK=128 per barrier -----
// grid 1024: m = bx>>2 (BM=32), s = bx&3 (K-slab of 2048). 512 thr, 8 waves:
// wr = wave>>2 (K-half of each 64-substep), wc = wave&3 (64-col quarter).
// Per outer iter (BK=128 = 2 substeps): 2 staging float4/thread issued early,
// nt passthrough + LDS write late, ONE barrier. Partials -> ws slab (s*2+wr),
// no atomics, no in-kernel cross-wave reduce. Staging layout = R7/R3 proven
// coalesced pattern (16 lanes x 64B contiguous per row).
__global__ __launch_bounds__(512, 6) void k2_gemm(
    const float* __restrict__ adj,
    const __hip_bfloat16* __restrict__ xtT,
    float* __restrict__ out_h,
    float* __restrict__ out_adj,
    float* __restrict__ part)          // nullptr -> atomicAdd into out_h
{
    __shared__ __align__(16) __hip_bfloat16 As[2][32][136];   // 17.4 KB

    const int t     = threadIdx.x;
    const int lane  = t & 63;
    const int wave  = t >> 6;
    const int wr    = wave >> 2;
    const int wc    = wave & 3;
    const int bx    = blockIdx.x;
    const int m0    = (bx >> 2) * 32;
    const int s     = bx & 3;
    const int kbase = s * 2048;

    const int srow = t >> 4;          // 0..31
    const int sj   = t & 15;          // 16B slot within 64-float substep
    const float* aptr = adj     + (size_t)(m0 + srow) * 8192 + kbase + sj * 4;
    float*       optr = out_adj + (size_t)(m0 + srow) * 8192 + kbase + sj * 4;

    const int arow = lane & 15;
    const int g8   = 8 * (lane >> 4);
    const __hip_bfloat16* bbase =
        xtT + (size_t)(wc * 64 + arow) * 8192 + kbase + wr * 32 + g8;

    f32x4 acc[2][4];
    #pragma unroll
    for (int i = 0; i < 2; i++)
        #pragma unroll
        for (int j = 0; j < 4; j++) acc[i][j] = (f32x4){0.f, 0.f, 0.f, 0.f};

    float4 T0, T1;
    // prologue: stage outer-tile 0 (2 substeps), passthrough + LDS
    T0 = *(const float4*)(aptr);
    T1 = *(const float4*)(aptr + 64);
    nt_store4(T0, optr);
    nt_store4(T1, optr + 64);
    *(ushort4*)(&As[0][srow][sj * 4])      = cvt4_bf16(T0);
    *(ushort4*)(&As[0][srow][64 + sj * 4]) = cvt4_bf16(T1);
    __syncthreads();

    int cur = 0;
    for (int kt = 0; kt < 16; kt++) {          // 16 outer iters of BK=128
        const bool hn = (kt + 1 < 16);
        if (hn) {   // issue-early: next outer tile (2 x float4)
            T0 = *(const float4*)(aptr + (kt + 1) * 128);
            T1 = *(const float4*)(aptr + (kt + 1) * 128 + 64);
        }

        #pragma unroll
        for (int sub = 0; sub < 2; sub++) {
            const int kcol = kt * 128 + sub * 64;
            short8v bf0 = *(const short8v*)(bbase + kcol);
            short8v bf1 = *(const short8v*)(bbase + (size_t)16 * 8192 + kcol);
            short8v bf2 = *(const short8v*)(bbase + (size_t)32 * 8192 + kcol);
            short8v bf3 = *(const short8v*)(bbase + (size_t)48 * 8192 + kcol);
            short8v a0  = *(const short8v*)(&As[cur][arow][sub * 64 + wr * 32 + g8]);
            short8v a1  = *(const short8v*)(&As[cur][16 + arow][sub * 64 + wr * 32 + g8]);

            acc[0][0] = __builtin_amdgcn_mfma_f32_16x16x32_bf16(a0, bf0, acc[0][0], 0, 0, 0);
            acc[0][1] = __builtin_amdgcn_mfma_f32_16x16x32_bf16(a0, bf1, acc[0][1], 0, 0, 0);
            acc[0][2] = __builtin_amdgcn_mfma_f32_16x16x32_bf16(a0, bf2, acc[0][2], 0, 0, 0);
            acc[0][3] = __builtin_amdgcn_mfma_f32_16x16x32_bf16(a0, bf3, acc[0][3], 0, 0, 0);
            acc[1][0] = __builtin_amdgcn_mfma_f32_16x16x32_bf16(a1, bf0, acc[1][0], 0, 0, 0);
            acc[1][1] = __builtin_amdgcn_mfma_f32_16x16x32_bf16(a1, bf1, acc[1][1], 0, 0, 0);
            acc[1][2] = __builtin_amdgcn_mfma_f32_16x16x32_bf16(a1, bf2, acc[1][2], 0, 0, 0);
            acc[1][3] = __builtin_amdgcn_mfma_f32_16x16x32_bf16(a1, bf3, acc[1][3], 0, 0, 0);
        }

        if (hn) {   // write-late: nt passthrough + next LDS buffer
            nt_store4(T0, optr + (kt + 1) * 128);
            nt_store4(T1, optr + (kt + 1) * 128 + 64);
            *(ushort4*)(&As[cur ^ 1][srow][sj * 4])      = cvt4_bf16(T0);
            *(ushort4*)(&As[cur ^ 1][srow][64 + sj * 4]) = cvt4_bf16(T1);
        }
        __syncthreads();
        cur ^= 1;
    }

    // emit wr-partials to ws slab (s*2+wr); C layout: col=lane&15, row=4*(lane>>4)+q
    const int crow0 = 4 * (lane >> 4);
    const int ccol  = lane & 15;
    if (part) {
        float* pb = part + (size_t)(s * 2 + wr) * N_NODES * D_DIM;
        #pragma unroll
        for (int mf = 0; mf < 2; mf++)
            #pragma unroll
            for (int nf = 0; nf < 4; nf++)
                #pragma unroll
                for (int q = 0; q < 4; q++)
                    pb[(size_t)(m0 + mf * 16 + crow0 + q) * 256
                       + wc * 64 + nf * 16 + ccol] = acc[mf][nf][q];
    } else {
        #pragma unroll
        for (int mf = 0; mf < 2; mf++)
            #pragma unroll
            for (int nf = 0; nf < 4; nf++)
                #pragma unroll
                for (int q = 0; q < 4; q++)
                    atomicAdd(out_h + (size_t)(m0 + mf * 16 + crow0 + q) * 256
                              + wc * 64 + nf * 16 + ccol, acc[mf][nf][q]);
    }
}

// ---------------- K3: reduce 8 partial slabs + hyperbolic epilogue ----------
__global__ __launch_bounds__(256) void k3_epilogue(
    float* __restrict__ h, const float* __restrict__ part)
{
    const int t = threadIdx.x;
    const int r = blockIdx.x * 16 + (t >> 4);
    const int j = t & 15;
    float* p = h + (size_t)r * 256 + j * 16;

    float4 v[4];
    if (part) {
        const size_t base = (size_t)r * 256 + j * 16;
        const size_t slab = (size_t)N_NODES * D_DIM;
        #pragma unroll
        for (int i = 0; i < 4; i++) {
            float4 a = *(const float4*)(part + base + 4 * i);
            #pragma unroll
            for (int sl = 1; sl < 8; sl++) {
                float4 b = *(const float4*)(part + sl * slab + base + 4 * i);
                a.x += b.x; a.y += b.y; a.z += b.z; a.w += b.w;
            }
            v[i] = a;
        }
    } else {
        #pragma unroll
        for (int i = 0; i < 4; i++) v[i] = *(const float4*)(p + 4 * i);
    }

    float s2 = 0.f, sp = 0.f;
    #pragma unroll
    for (int i = 0; i < 4; i++) {
        s2 += v[i].x * v[i].x + v[i].y * v[i].y + v[i].z * v[i].z + v[i].w * v[i].w;
        float px = fmaxf(v[i].x, 0.f), py = fmaxf(v[i].y, 0.f);
        float pz = fmaxf(v[i].z, 0.f), pw = fmaxf(v[i].w, 0.f);
        sp += px * px + py * py + pz * pz + pw * pw;
    }
    s2 += __shfl_xor(s2, 1); s2 += __shfl_xor(s2, 2); s2 += __shfl_xor(s2, 4); s2 += __shfl_xor(s2, 8);
    sp += __shfl_xor(sp, 1); sp += __shfl_xor(sp, 2); sp += __shfl_xor(sp, 4); sp += __shfl_xor(sp, 8);

    float ns = fmaxf(sqrtf(s2), 1e-15f);
    float t1 = tanhf(ns);
    float alpha = (t1 > 0.996f) ? (0.996f / ns) : (t1 / ns);   // expmap0+proj
    float nh = fminf(t1, 0.996f);
    float beta = artanh_clip(nh) / nh;                          // logmap0
    float ba = beta * alpha;
    float nxt = fmaxf(ba * sqrtf(sp), 1e-15f);                  // ||relu(xt)||
    float t2 = tanhf(nxt);
    float delta = (t2 > 0.996f) ? (0.996f / nxt) : (t2 / nxt);  // expmap0+proj
    float F = delta * ba;

    #pragma unroll
    for (int i = 0; i < 4; i++) {
        float4 o;
        o.x = F * fmaxf(v[i].x, 0.f);
        o.y = F * fmaxf(v[i].y, 0.f);
        o.z = F * fmaxf(v[i].z, 0.f);
        o.w = F * fmaxf(v[i].w, 0.f);
        *(float4*)(p + 4 * i) = o;
    }
}

extern "C" void kernel_launch(void* const* d_in, const int* in_sizes, int n_in,
                              void* d_out, int out_size, void* d_ws, size_t ws_size,
                              hipStream_t stream)
{
    const float* x    = (const float*)d_in[0];
    const float* adj  = (const float*)d_in[1];
    const float* W    = (const float*)d_in[2];
    const float* bias = (const float*)d_in[3];

    float* out_h   = (float*)d_out;
    float* out_adj = out_h + (size_t)N_NODES * D_DIM;

    const size_t xtT_bytes = (size_t)D_DIM * N_NODES * 2;       // 4 MB
    __hip_bfloat16* xtT = (__hip_bfloat16*)d_ws;
    float* hbg = (float*)((char*)d_ws + xtT_bytes);             // hb[256] + b2

    const size_t part_off   = xtT_bytes + 4096;
    const size_t part_bytes = (size_t)8 * N_NODES * D_DIM * sizeof(float);  // 64 MB
    const bool use_part = ws_size >= part_off + part_bytes;
    float* part = use_part ? (float*)((char*)d_ws + part_off) : nullptr;

    k0_bias<<<1, 256, 0, stream>>>(bias, hbg);
    k1_hyplinear<<<512, 256, 0, stream>>>(x, W, hbg, xtT);
    if (!use_part)
        hipMemsetAsync(out_h, 0, (size_t)N_NODES * D_DIM * sizeof(float), stream);
    k2_gemm<<<1024, 512, 0, stream>>>(adj, xtT, out_h, out_adj, part);
    k3_epilogue<<<512, 256, 0, stream>>>(out_h, part);
}